// Round 1
// 3895.589 us; speedup vs baseline: 1.7799x; 1.7799x over previous
//
#include <hip/hip_runtime.h>
#include <cstdint>
#include <cstddef>

// Problem constants (from reference)
#define BSZ   2
#define T_SEQ 1024
#define D_EMB 1024
#define NH    16
#define NKV   4
#define HS    64
#define NL    6
#define VOCAB 32000
#define FFH   4096
#define QKVC  (D_EMB + 2 * NKV * HS)   // 1536: fused q|k|v column dim

typedef __bf16 bf16x8 __attribute__((ext_vector_type(8)));
typedef float  f32x4  __attribute__((ext_vector_type(4)));
typedef unsigned short u16x4 __attribute__((ext_vector_type(4)));

__device__ __forceinline__ unsigned short f2bf(float f) {
    // round-to-nearest-even f32 -> bf16 (finite inputs only)
    unsigned u = __float_as_uint(f);
    u += 0x7fffu + ((u >> 16) & 1u);
    return (unsigned short)(u >> 16);
}

// async global->LDS, 16B per lane; LDS dest is wave-uniform base + lane*16
#define GLOAD_LDS16(gptr, lptr)                                                   \
    __builtin_amdgcn_global_load_lds(                                             \
        (const __attribute__((address_space(1))) void*)(gptr),                    \
        (__attribute__((address_space(3))) void*)(lptr), 16, 0, 0)

// ---------------- embedding: x[b,t,:] = tok_emb[tok] + pos_emb[t] ----------------
__global__ void embed_kernel(const int* __restrict__ tok,
                             const float* __restrict__ tok_emb,
                             const float* __restrict__ pos_emb,
                             float* __restrict__ x) {
    int row = blockIdx.x;               // b*T + t
    int t   = row & (T_SEQ - 1);
    int tk  = tok[row];
    int tid = threadIdx.x;              // 256 threads * float4 = 1024
    f32x4 te = ((const f32x4*)(tok_emb + (size_t)tk * D_EMB))[tid];
    f32x4 pe = ((const f32x4*)(pos_emb + (size_t)t  * D_EMB))[tid];
    ((f32x4*)(x + (size_t)row * D_EMB))[tid] = te + pe;
}

// ---------------- layernorm: out_bf16 = (x-mu)*rsqrt(var+eps)*g + b ----------------
__global__ void ln_kernel(const float* __restrict__ x,
                          const float* __restrict__ g,
                          const float* __restrict__ b,
                          unsigned short* __restrict__ out) {
    int row = blockIdx.x;
    int tid = threadIdx.x;
    f32x4 v = ((const f32x4*)(x + (size_t)row * D_EMB))[tid];
    float s  = v.x + v.y + v.z + v.w;
    float s2 = v.x*v.x + v.y*v.y + v.z*v.z + v.w*v.w;
#pragma unroll
    for (int o = 32; o; o >>= 1) { s += __shfl_down(s, o); s2 += __shfl_down(s2, o); }
    __shared__ float sm[8];
    int wave = tid >> 6, lane = tid & 63;
    if (lane == 0) { sm[wave] = s; sm[4 + wave] = s2; }
    __syncthreads();
    s  = sm[0] + sm[1] + sm[2] + sm[3];
    s2 = sm[4] + sm[5] + sm[6] + sm[7];
    float mu   = s * (1.0f / D_EMB);
    float var  = s2 * (1.0f / D_EMB) - mu * mu;
    float rstd = rsqrtf(var + 1e-5f);
    f32x4 gv = ((const f32x4*)g)[tid];
    f32x4 bv = ((const f32x4*)b)[tid];
    f32x4 o4 = (v - mu) * rstd * gv + bv;
    u16x4 ob;
    ob.x = f2bf(o4.x); ob.y = f2bf(o4.y); ob.z = f2bf(o4.z); ob.w = f2bf(o4.w);
    ((u16x4*)(out + (size_t)row * D_EMB))[tid] = ob;
}

// ---------------- weight convert+transpose: src f32 [K][N] -> dst bf16 [N][K] ----------------
__device__ __forceinline__ void wconv_tile(const float* __restrict__ src,
                                           unsigned short* __restrict__ dst,
                                           int K, int N, int k0, int n0, int tid) {
    __shared__ float t[32][33];
    const int tx = tid & 31, ty = tid >> 5;
#pragma unroll
    for (int i = 0; i < 4; ++i)
        t[ty + i * 8][tx] = src[(size_t)(k0 + ty + i * 8) * N + n0 + tx];
    __syncthreads();
#pragma unroll
    for (int i = 0; i < 4; ++i)
        dst[(size_t)(n0 + ty + i * 8) * K + k0 + tx] = f2bf(t[tx][ty + i * 8]);
}

__global__ __launch_bounds__(256)
void wconv_kernel(const float* __restrict__ src, unsigned short* __restrict__ dst,
                  int K, int N) {
    wconv_tile(src, dst, K, N, blockIdx.x * 32, blockIdx.y * 32, threadIdx.x);
}

// one layer's 6 weight matrices in one grid (tile ranges hardcoded)
__global__ __launch_bounds__(256)
void wconv6_kernel(const float* __restrict__ Wq, const float* __restrict__ Wk,
                   const float* __restrict__ Wv, const float* __restrict__ Wo,
                   const float* __restrict__ W1, const float* __restrict__ W2,
                   unsigned short* __restrict__ qkvT, unsigned short* __restrict__ WoT,
                   unsigned short* __restrict__ W1T, unsigned short* __restrict__ W2T) {
    int t = blockIdx.x;
    const float* src; unsigned short* dst; int K, N;
    if (t < 1024)      {            src = Wq; dst = qkvT;                         K = 1024; N = 1024; }
    else if (t < 1280) { t -= 1024; src = Wk; dst = qkvT + (size_t)1024 * 1024;   K = 1024; N = 256;  }
    else if (t < 1536) { t -= 1280; src = Wv; dst = qkvT + (size_t)1280 * 1024;   K = 1024; N = 256;  }
    else if (t < 2560) { t -= 1536; src = Wo; dst = WoT;                          K = 1024; N = 1024; }
    else if (t < 6656) { t -= 2560; src = W1; dst = W1T;                          K = 1024; N = 4096; }
    else               { t -= 6656; src = W2; dst = W2T;                          K = 4096; N = 1024; }
    int nt = N >> 5;
    wconv_tile(src, dst, K, N, (t / nt) * 32, (t % nt) * 32, threadIdx.x);
}

// ---------------- bf16-MFMA GEMM (m97 structure): C = A[M][K]bf16 @ B^T[N][K]bf16 ----------------
// 128x128 tile / block (4 waves, each 64x64 = 4x4 mfma 16x16x32), BK=32.
// LDS [128][32] bf16 linear (row stride 64B -> conflict-free ds_read_b128),
// staged via global_load_lds width=16 (no VGPR round-trip, no in-kernel cvt).
template<int BIAS, int RES, int RELU, int OUTBF>
__global__ __launch_bounds__(256)
void gemm_kernel(const unsigned short* __restrict__ A, const unsigned short* __restrict__ B,
                 const float* __restrict__ bias, const float* __restrict__ Res,
                 void* __restrict__ Cv, int M, int N, int K) {
    (void)M;
    constexpr int BK = 32;
    __shared__ unsigned short Asm[128 * BK];
    __shared__ unsigned short Bsm[128 * BK];

    const int tid  = threadIdx.x;
    const int lane = tid & 63;
    const int wave = tid >> 6;
    const int quad = lane >> 4;
    const int l16  = lane & 15;
    const int m0   = blockIdx.x * 128;
    const int n0   = blockIdx.y * 128;
    const int wm   = (wave >> 1) * 64;
    const int wn   = (wave & 1) * 64;

    // staging: wave w owns rows [w*32, w*32+32); one gload = 16 rows x 64B
    const int srow = lane >> 2;          // 0..15 row within 16-row group
    const int sk   = (lane & 3) * 8;     // 8-elem (16B) chunk within BK
    const unsigned short* Abase = A + (size_t)(m0 + wave * 32 + srow) * K + sk;
    const unsigned short* Bbase = B + (size_t)(n0 + wave * 32 + srow) * K + sk;
    unsigned short* AsmW = &Asm[(wave * 32) * BK];
    unsigned short* BsmW = &Bsm[(wave * 32) * BK];

    f32x4 acc[4][4] = {};

    for (int k0 = 0; k0 < K; k0 += BK) {
        __syncthreads();                 // previous iteration's fragment reads done
        GLOAD_LDS16(Abase + k0,               AsmW);
        GLOAD_LDS16(Abase + k0 + 16 * (size_t)K, AsmW + 16 * BK);
        GLOAD_LDS16(Bbase + k0,               BsmW);
        GLOAD_LDS16(Bbase + k0 + 16 * (size_t)K, BsmW + 16 * BK);
        __syncthreads();                 // drains vmcnt(0): tiles resident
        bf16x8 af[4], bfr[4];
#pragma unroll
        for (int mi = 0; mi < 4; ++mi)
            af[mi] = *(const bf16x8*)&Asm[(wm + mi * 16 + l16) * BK + quad * 8];
#pragma unroll
        for (int ni = 0; ni < 4; ++ni)
            bfr[ni] = *(const bf16x8*)&Bsm[(wn + ni * 16 + l16) * BK + quad * 8];
#pragma unroll
        for (int mi = 0; mi < 4; ++mi)
#pragma unroll
            for (int ni = 0; ni < 4; ++ni)
                acc[mi][ni] = __builtin_amdgcn_mfma_f32_16x16x32_bf16(af[mi], bfr[ni], acc[mi][ni], 0, 0, 0);
    }

    // ---- epilogue: D[row=quad*4+r][col=lane&15] ----
#pragma unroll
    for (int mi = 0; mi < 4; ++mi) {
#pragma unroll
        for (int ni = 0; ni < 4; ++ni) {
            int col = n0 + wn + ni * 16 + l16;
            float bv = BIAS ? bias[col] : 0.0f;
#pragma unroll
            for (int r = 0; r < 4; ++r) {
                int row = m0 + wm + mi * 16 + quad * 4 + r;
                float val = acc[mi][ni][r] + bv;
                if (RES)  val += Res[(size_t)row * N + col];
                if (RELU) val = fmaxf(val, 0.0f);
                if (OUTBF) ((unsigned short*)Cv)[(size_t)row * N + col] = f2bf(val);
                else       ((float*)Cv)[(size_t)row * N + col] = val;
            }
        }
    }
}

// ---------------- causal GQA flash attention (f32 in from fused qkv, bf16 out) ----------------
// block = (qb, h, b): 64 q-rows, 256 thr; thread (r = tid>>2, c = tid&3) owns q-row r, dims [c*16, c*16+16)
__global__ __launch_bounds__(256)
void attn_kernel(const float* __restrict__ QKV, unsigned short* __restrict__ Y) {
    constexpr int LP = 68;                  // padded row stride (floats)
    __shared__ float Ks[64 * LP];
    __shared__ float Vs[64 * LP];
    __shared__ float Ps[64 * LP];

    const int qb = blockIdx.x, h = blockIdx.y, b = blockIdx.z;
    const int kvh = h >> 2;                 // REP = 4
    const int tid = threadIdx.x;
    const int r = tid >> 2, c = tid & 3;
    const int q0 = qb * 64;

    const float* qrow = QKV + (size_t)(b * T_SEQ + q0 + r) * QKVC + h * HS;
    f32x4 q4[16];
#pragma unroll
    for (int j = 0; j < 16; ++j) q4[j] = *(const f32x4*)(qrow + j * 4);

    float o[16];
#pragma unroll
    for (int d = 0; d < 16; ++d) o[d] = 0.f;
    float m = -1e30f, l = 0.f;

    for (int kt = 0; kt <= qb; ++kt) {
        int k0 = kt * 64;
        __syncthreads();                    // protect K/V overwrite
#pragma unroll
        for (int i = 0; i < 4; ++i) {
            int idx = i * 256 + tid;
            int row = idx >> 4, d4 = (idx & 15) << 2;
            size_t gofs = (size_t)(b * T_SEQ + k0 + row) * QKVC + kvh * HS + d4;
            *(f32x4*)&Ks[row * LP + d4] = *(const f32x4*)(QKV + gofs + D_EMB);
            *(f32x4*)&Vs[row * LP + d4] = *(const f32x4*)(QKV + gofs + D_EMB + NKV * HS);
        }
        __syncthreads();

        float s[16];
#pragma unroll
        for (int kk = 0; kk < 16; ++kk) {
            int k = c * 16 + kk;
            const f32x4* krow = (const f32x4*)&Ks[k * LP];
            float a = 0.f;
#pragma unroll
            for (int j = 0; j < 16; ++j) {
                f32x4 kv = krow[j];
                a += q4[j].x * kv.x + q4[j].y * kv.y + q4[j].z * kv.z + q4[j].w * kv.w;
            }
            a *= 0.125f;                    // HS^-0.5
            if (k0 + k > q0 + r) a = -1e30f;
            s[kk] = a;
        }
        float mx = s[0];
#pragma unroll
        for (int kk = 1; kk < 16; ++kk) mx = fmaxf(mx, s[kk]);
        mx = fmaxf(mx, __shfl_xor(mx, 1));
        mx = fmaxf(mx, __shfl_xor(mx, 2));
        float mnew  = fmaxf(m, mx);
        float alpha = __expf(m - mnew);
        float ls = 0.f;
#pragma unroll
        for (int kk = 0; kk < 16; ++kk) { s[kk] = __expf(s[kk] - mnew); ls += s[kk]; }
        ls += __shfl_xor(ls, 1);
        ls += __shfl_xor(ls, 2);
        l = l * alpha + ls;
        m = mnew;
#pragma unroll
        for (int kk = 0; kk < 16; ++kk) Ps[r * LP + c * 16 + kk] = s[kk];
        // Ps row is produced & consumed by the same wave (lanes 4r..4r+3) -> no barrier needed
#pragma unroll
        for (int d = 0; d < 16; ++d) o[d] *= alpha;
        for (int k = 0; k < 64; ++k) {
            float p = Ps[r * LP + k];
            const f32x4* vrow = (const f32x4*)&Vs[k * LP + c * 16];
#pragma unroll
            for (int dj = 0; dj < 4; ++dj) {
                f32x4 vv = vrow[dj];
                o[dj * 4 + 0] += p * vv.x; o[dj * 4 + 1] += p * vv.y;
                o[dj * 4 + 2] += p * vv.z; o[dj * 4 + 3] += p * vv.w;
            }
        }
    }
    float inv = 1.0f / l;
    unsigned short* yrow = Y + (size_t)(b * T_SEQ + q0 + r) * D_EMB + h * HS + c * 16;
#pragma unroll
    for (int dj = 0; dj < 4; ++dj) {
        u16x4 ov;
        ov.x = f2bf(o[dj * 4 + 0] * inv); ov.y = f2bf(o[dj * 4 + 1] * inv);
        ov.z = f2bf(o[dj * 4 + 2] * inv); ov.w = f2bf(o[dj * 4 + 3] * inv);
        *(u16x4*)(yrow + dj * 4) = ov;
    }
}

// ---------------- launch ----------------
extern "C" void kernel_launch(void* const* d_in, const int* in_sizes, int n_in,
                              void* d_out, int out_size, void* d_ws, size_t ws_size,
                              hipStream_t stream) {
    (void)in_sizes; (void)n_in; (void)out_size; (void)ws_size;
    const int*   tokens  = (const int*)  d_in[0];
    const float* tok_emb = (const float*)d_in[1];
    const float* pos_emb = (const float*)d_in[2];
    const float* ln1_g   = (const float*)d_in[3];
    const float* ln1_b   = (const float*)d_in[4];
    const float* Wq      = (const float*)d_in[5];
    const float* Wk      = (const float*)d_in[6];
    const float* Wv      = (const float*)d_in[7];
    const float* Wo      = (const float*)d_in[8];
    const float* bo      = (const float*)d_in[9];
    const float* ln2_g   = (const float*)d_in[10];
    const float* ln2_b   = (const float*)d_in[11];
    const float* W1      = (const float*)d_in[12];
    const float* b1      = (const float*)d_in[13];
    const float* W2      = (const float*)d_in[14];
    const float* b2      = (const float*)d_in[15];
    const float* lnf_g   = (const float*)d_in[16];
    const float* lnf_b   = (const float*)d_in[17];
    const float* Wlm     = (const float*)d_in[18];
    const float* blm     = (const float*)d_in[19];
    float* out = (float*)d_out;

    const int M = BSZ * T_SEQ;   // 2048

    char* p = (char*)d_ws;
    float*          x     = (float*)p;          p += (size_t)M * D_EMB * 4;        //  8 MB f32 residual
    float*          qkv   = (float*)p;          p += (size_t)M * QKVC  * 4;        // 12 MB f32 fused q|k|v
    unsigned short* hbf   = (unsigned short*)p; p += (size_t)M * D_EMB * 2;        //  4 MB bf16 LN out
    unsigned short* ybf   = (unsigned short*)p; p += (size_t)M * D_EMB * 2;        //  4 MB bf16 attn out
    unsigned short* ffnbf = (unsigned short*)p; p += (size_t)M * FFH   * 2;        // 16 MB bf16 relu out
    unsigned short* qkvT  = (unsigned short*)p; p += (size_t)QKVC * D_EMB * 2;     //  3 MB W_qkv^T
    unsigned short* WoT   = (unsigned short*)p; p += (size_t)D_EMB * D_EMB * 2;    //  2 MB
    unsigned short* W1T   = (unsigned short*)p; p += (size_t)FFH * D_EMB * 2;      //  8 MB
    unsigned short* W2T   = (unsigned short*)p; p += (size_t)D_EMB * FFH * 2;      //  8 MB
    unsigned short* WlmT  = (unsigned short*)p; p += (size_t)VOCAB * D_EMB * 2;    // 64 MB

    embed_kernel<<<M, 256, 0, stream>>>(tokens, tok_emb, pos_emb, x);

    for (int l = 0; l < NL; ++l) {
        wconv6_kernel<<<10752, 256, 0, stream>>>(
            Wq + (size_t)l * D_EMB * D_EMB, Wk + (size_t)l * D_EMB * NKV * HS,
            Wv + (size_t)l * D_EMB * NKV * HS, Wo + (size_t)l * D_EMB * D_EMB,
            W1 + (size_t)l * D_EMB * FFH, W2 + (size_t)l * FFH * D_EMB,
            qkvT, WoT, W1T, W2T);
        ln_kernel<<<M, 256, 0, stream>>>(x, ln1_g + l * D_EMB, ln1_b + l * D_EMB, hbf);
        gemm_kernel<0,0,0,0><<<dim3(M/128, QKVC/128), 256, 0, stream>>>(
            hbf, qkvT, nullptr, nullptr, qkv, M, QKVC, D_EMB);
        attn_kernel<<<dim3(T_SEQ/64, NH, BSZ), 256, 0, stream>>>(qkv, ybf);
        gemm_kernel<1,1,0,0><<<dim3(M/128, D_EMB/128), 256, 0, stream>>>(
            ybf, WoT, bo + l * D_EMB, x, x, M, D_EMB, D_EMB);
        ln_kernel<<<M, 256, 0, stream>>>(x, ln2_g + l * D_EMB, ln2_b + l * D_EMB, hbf);
        gemm_kernel<1,0,1,1><<<dim3(M/128, FFH/128), 256, 0, stream>>>(
            hbf, W1T, b1 + l * FFH, nullptr, ffnbf, M, FFH, D_EMB);
        gemm_kernel<1,1,0,0><<<dim3(M/128, D_EMB/128), 256, 0, stream>>>(
            ffnbf, W2T, b2 + l * D_EMB, x, x, M, D_EMB, FFH);
    }
    ln_kernel<<<M, 256, 0, stream>>>(x, lnf_g, lnf_b, hbf);
    wconv_kernel<<<dim3(D_EMB/32, VOCAB/32), 256, 0, stream>>>(Wlm, WlmT, D_EMB, VOCAB);
    gemm_kernel<1,0,0,0><<<dim3(M/128, VOCAB/128), 256, 0, stream>>>(
        hbf, WlmT, blm, nullptr, out, M, VOCAB, D_EMB);
}

// Round 2
// 2092.275 us; speedup vs baseline: 3.3140x; 1.8619x over previous
//
#include <hip/hip_runtime.h>
#include <cstdint>
#include <cstddef>

// Problem constants (from reference)
#define BSZ   2
#define T_SEQ 1024
#define D_EMB 1024
#define NH    16
#define NKV   4
#define HS    64
#define NL    6
#define VOCAB 32000
#define FFH   4096
#define QKVC  (D_EMB + 2 * NKV * HS)   // 1536: fused q|k|v column dim

typedef __bf16 bf16x8 __attribute__((ext_vector_type(8)));
typedef float  f32x4  __attribute__((ext_vector_type(4)));
typedef unsigned short u16x4 __attribute__((ext_vector_type(4)));

__device__ __forceinline__ unsigned short f2bf(float f) {
    // round-to-nearest-even f32 -> bf16 (finite inputs only)
    unsigned u = __float_as_uint(f);
    u += 0x7fffu + ((u >> 16) & 1u);
    return (unsigned short)(u >> 16);
}

// async global->LDS, 16B per lane; LDS dest is wave-uniform base + lane*16
#define GLOAD_LDS16(gptr, lptr)                                                   \
    __builtin_amdgcn_global_load_lds(                                             \
        (const __attribute__((address_space(1))) void*)(gptr),                    \
        (__attribute__((address_space(3))) void*)(lptr), 16, 0, 0)

// ---------------- embedding: x[b,t,:] = tok_emb[tok] + pos_emb[t] ----------------
__global__ void embed_kernel(const int* __restrict__ tok,
                             const float* __restrict__ tok_emb,
                             const float* __restrict__ pos_emb,
                             float* __restrict__ x) {
    int row = blockIdx.x;               // b*T + t
    int t   = row & (T_SEQ - 1);
    int tk  = tok[row];
    int tid = threadIdx.x;              // 256 threads * float4 = 1024
    f32x4 te = ((const f32x4*)(tok_emb + (size_t)tk * D_EMB))[tid];
    f32x4 pe = ((const f32x4*)(pos_emb + (size_t)t  * D_EMB))[tid];
    ((f32x4*)(x + (size_t)row * D_EMB))[tid] = te + pe;
}

// ---------------- layernorm: out_bf16 = (x-mu)*rsqrt(var+eps)*g + b ----------------
__global__ void ln_kernel(const float* __restrict__ x,
                          const float* __restrict__ g,
                          const float* __restrict__ b,
                          unsigned short* __restrict__ out) {
    int row = blockIdx.x;
    int tid = threadIdx.x;
    f32x4 v = ((const f32x4*)(x + (size_t)row * D_EMB))[tid];
    float s  = v.x + v.y + v.z + v.w;
    float s2 = v.x*v.x + v.y*v.y + v.z*v.z + v.w*v.w;
#pragma unroll
    for (int o = 32; o; o >>= 1) { s += __shfl_down(s, o); s2 += __shfl_down(s2, o); }
    __shared__ float sm[8];
    int wave = tid >> 6, lane = tid & 63;
    if (lane == 0) { sm[wave] = s; sm[4 + wave] = s2; }
    __syncthreads();
    s  = sm[0] + sm[1] + sm[2] + sm[3];
    s2 = sm[4] + sm[5] + sm[6] + sm[7];
    float mu   = s * (1.0f / D_EMB);
    float var  = s2 * (1.0f / D_EMB) - mu * mu;
    float rstd = rsqrtf(var + 1e-5f);
    f32x4 gv = ((const f32x4*)g)[tid];
    f32x4 bv = ((const f32x4*)b)[tid];
    f32x4 o4 = (v - mu) * rstd * gv + bv;
    u16x4 ob;
    ob.x = f2bf(o4.x); ob.y = f2bf(o4.y); ob.z = f2bf(o4.z); ob.w = f2bf(o4.w);
    ((u16x4*)(out + (size_t)row * D_EMB))[tid] = ob;
}

// ---------------- weight convert+transpose: src f32 [K][N] -> dst bf16 [N][K] ----------------
__device__ __forceinline__ void wconv_tile(const float* __restrict__ src,
                                           unsigned short* __restrict__ dst,
                                           int K, int N, int k0, int n0, int tid) {
    __shared__ float t[32][33];
    const int tx = tid & 31, ty = tid >> 5;
#pragma unroll
    for (int i = 0; i < 4; ++i)
        t[ty + i * 8][tx] = src[(size_t)(k0 + ty + i * 8) * N + n0 + tx];
    __syncthreads();
#pragma unroll
    for (int i = 0; i < 4; ++i)
        dst[(size_t)(n0 + ty + i * 8) * K + k0 + tx] = f2bf(t[tx][ty + i * 8]);
}

__global__ __launch_bounds__(256)
void wconv_kernel(const float* __restrict__ src, unsigned short* __restrict__ dst,
                  int K, int N) {
    wconv_tile(src, dst, K, N, blockIdx.x * 32, blockIdx.y * 32, threadIdx.x);
}

// one layer's 6 weight matrices in one grid (tile ranges hardcoded)
__global__ __launch_bounds__(256)
void wconv6_kernel(const float* __restrict__ Wq, const float* __restrict__ Wk,
                   const float* __restrict__ Wv, const float* __restrict__ Wo,
                   const float* __restrict__ W1, const float* __restrict__ W2,
                   unsigned short* __restrict__ qkvT, unsigned short* __restrict__ WoT,
                   unsigned short* __restrict__ W1T, unsigned short* __restrict__ W2T) {
    int t = blockIdx.x;
    const float* src; unsigned short* dst; int K, N;
    if (t < 1024)      {            src = Wq; dst = qkvT;                         K = 1024; N = 1024; }
    else if (t < 1280) { t -= 1024; src = Wk; dst = qkvT + (size_t)1024 * 1024;   K = 1024; N = 256;  }
    else if (t < 1536) { t -= 1280; src = Wv; dst = qkvT + (size_t)1280 * 1024;   K = 1024; N = 256;  }
    else if (t < 2560) { t -= 1536; src = Wo; dst = WoT;                          K = 1024; N = 1024; }
    else if (t < 6656) { t -= 2560; src = W1; dst = W1T;                          K = 1024; N = 4096; }
    else               { t -= 6656; src = W2; dst = W2T;                          K = 4096; N = 1024; }
    int nt = N >> 5;
    wconv_tile(src, dst, K, N, (t / nt) * 32, (t % nt) * 32, threadIdx.x);
}

// ---------------- bf16-MFMA GEMM (m97 structure): C = A[M][K]bf16 @ B^T[N][K]bf16 ----------------
template<int BIAS, int RES, int RELU, int OUTBF>
__global__ __launch_bounds__(256)
void gemm_kernel(const unsigned short* __restrict__ A, const unsigned short* __restrict__ B,
                 const float* __restrict__ bias, const float* __restrict__ Res,
                 void* __restrict__ Cv, int M, int N, int K) {
    (void)M;
    constexpr int BK = 32;
    __shared__ unsigned short Asm[128 * BK];
    __shared__ unsigned short Bsm[128 * BK];

    const int tid  = threadIdx.x;
    const int lane = tid & 63;
    const int wave = tid >> 6;
    const int quad = lane >> 4;
    const int l16  = lane & 15;
    const int m0   = blockIdx.x * 128;
    const int n0   = blockIdx.y * 128;
    const int wm   = (wave >> 1) * 64;
    const int wn   = (wave & 1) * 64;

    // staging: wave w owns rows [w*32, w*32+32); one gload = 16 rows x 64B
    const int srow = lane >> 2;          // 0..15 row within 16-row group
    const int sk   = (lane & 3) * 8;     // 8-elem (16B) chunk within BK
    const unsigned short* Abase = A + (size_t)(m0 + wave * 32 + srow) * K + sk;
    const unsigned short* Bbase = B + (size_t)(n0 + wave * 32 + srow) * K + sk;
    unsigned short* AsmW = &Asm[(wave * 32) * BK];
    unsigned short* BsmW = &Bsm[(wave * 32) * BK];

    f32x4 acc[4][4] = {};

    for (int k0 = 0; k0 < K; k0 += BK) {
        __syncthreads();                 // previous iteration's fragment reads done
        GLOAD_LDS16(Abase + k0,               AsmW);
        GLOAD_LDS16(Abase + k0 + 16 * (size_t)K, AsmW + 16 * BK);
        GLOAD_LDS16(Bbase + k0,               BsmW);
        GLOAD_LDS16(Bbase + k0 + 16 * (size_t)K, BsmW + 16 * BK);
        __syncthreads();                 // drains vmcnt(0): tiles resident
        bf16x8 af[4], bfr[4];
#pragma unroll
        for (int mi = 0; mi < 4; ++mi)
            af[mi] = *(const bf16x8*)&Asm[(wm + mi * 16 + l16) * BK + quad * 8];
#pragma unroll
        for (int ni = 0; ni < 4; ++ni)
            bfr[ni] = *(const bf16x8*)&Bsm[(wn + ni * 16 + l16) * BK + quad * 8];
#pragma unroll
        for (int mi = 0; mi < 4; ++mi)
#pragma unroll
            for (int ni = 0; ni < 4; ++ni)
                acc[mi][ni] = __builtin_amdgcn_mfma_f32_16x16x32_bf16(af[mi], bfr[ni], acc[mi][ni], 0, 0, 0);
    }

    // ---- epilogue: D[row=quad*4+r][col=lane&15] ----
#pragma unroll
    for (int mi = 0; mi < 4; ++mi) {
#pragma unroll
        for (int ni = 0; ni < 4; ++ni) {
            int col = n0 + wn + ni * 16 + l16;
            float bv = BIAS ? bias[col] : 0.0f;
#pragma unroll
            for (int r = 0; r < 4; ++r) {
                int row = m0 + wm + mi * 16 + quad * 4 + r;
                float val = acc[mi][ni][r] + bv;
                if (RES)  val += Res[(size_t)row * N + col];
                if (RELU) val = fmaxf(val, 0.0f);
                if (OUTBF) ((unsigned short*)Cv)[(size_t)row * N + col] = f2bf(val);
                else       ((float*)Cv)[(size_t)row * N + col] = val;
            }
        }
    }
}

// ---------------- causal GQA flash attention, MFMA bf16 ----------------
// block = (qb, h, b): 64 q-rows, 256 thr = 4 waves; wave owns 16 q-rows.
// Q in registers (A-frags); K in LDS [key][72] bf16; V transposed in LDS [d][72];
// S = mfma(Q,K) -> online softmax in C-layout regs -> P via wave-private LDS -> O += mfma(P,V^T).
__global__ __launch_bounds__(256)
void attn_kernel(const unsigned short* __restrict__ QKV, unsigned short* __restrict__ Y) {
    constexpr int LDK = 72;                 // 144 B row stride: bank rotation 4 dwords/row
    __shared__ unsigned short Ks[64 * LDK];
    __shared__ unsigned short Vt[64 * LDK];
    __shared__ unsigned short Ps[64 * LDK];

    const int qb = blockIdx.x, h = blockIdx.y, b = blockIdx.z;
    const int kvh = h >> 2;                 // REP = 4
    const int tid  = threadIdx.x;
    const int lane = tid & 63, wave = tid >> 6;
    const int quad = lane >> 4, l16 = lane & 15;
    const int q0 = qb * 64;
    const int wq = wave * 16;               // wave's q-row offset within tile

    // Q fragments: A-operand row = l16, k = kk*32 + quad*8
    const unsigned short* qp = QKV + (size_t)(b * T_SEQ + q0 + wq + l16) * QKVC + h * HS + quad * 8;
    const bf16x8 qf0 = *(const bf16x8*)qp;
    const bf16x8 qf1 = *(const bf16x8*)(qp + 32);

    f32x4 o[4] = {};                        // O: row = quad*4+r, col = ni*16+l16
    float m[4], l[4];
#pragma unroll
    for (int r = 0; r < 4; ++r) { m[r] = -1e30f; l[r] = 0.f; }

    const int kq  = tid & 63;               // staging: key index (coalesced-by-bank Vt writes)
    const int sd8 = (tid >> 6) * 8;         // staging: dim chunk base
    const int myqmax = q0 + wq + 15;        // wave's last q-row

    for (int kt = 0; kt <= qb; ++kt) {
        const int k0 = kt * 64;
        __syncthreads();                    // protect K/V overwrite (all waves, every iter)
#pragma unroll
        for (int i = 0; i < 2; ++i) {
            const int d8 = sd8 + i * 32;
            const unsigned short* kvrow = QKV + (size_t)(b * T_SEQ + k0 + kq) * QKVC + D_EMB + kvh * HS;
            *(bf16x8*)&Ks[kq * LDK + d8] = *(const bf16x8*)(kvrow + d8);
            union { bf16x8 v; unsigned short h[8]; } vv;
            vv.v = *(const bf16x8*)(kvrow + NKV * HS + d8);
#pragma unroll
            for (int j = 0; j < 8; ++j) Vt[(d8 + j) * LDK + kq] = vv.h[j];
        }
        __syncthreads();
        if (k0 > myqmax) continue;          // tile fully masked for this wave (barriers already done)

        // ---- S = Q @ K^T : 8 MFMA ----
        f32x4 s[4] = {};
#pragma unroll
        for (int ni = 0; ni < 4; ++ni) {
            bf16x8 kf0 = *(const bf16x8*)&Ks[(ni * 16 + l16) * LDK + quad * 8];
            bf16x8 kf1 = *(const bf16x8*)&Ks[(ni * 16 + l16) * LDK + 32 + quad * 8];
            s[ni] = __builtin_amdgcn_mfma_f32_16x16x32_bf16(qf0, kf0, s[ni], 0, 0, 0);
            s[ni] = __builtin_amdgcn_mfma_f32_16x16x32_bf16(qf1, kf1, s[ni], 0, 0, 0);
        }

        // ---- online softmax: row = quad*4+r spread over 16 l16-lanes x 4 ni ----
        float p[4][4];                      // [ni][r]
#pragma unroll
        for (int r = 0; r < 4; ++r) {
            const int qrow = q0 + wq + quad * 4 + r;
            float sv[4]; float mx = -1e30f;
#pragma unroll
            for (int ni = 0; ni < 4; ++ni) {
                float v = s[ni][r] * 0.125f;            // HS^-0.5
                if (k0 + ni * 16 + l16 > qrow) v = -1e30f;
                sv[ni] = v; mx = fmaxf(mx, v);
            }
            mx = fmaxf(mx, __shfl_xor(mx, 1));
            mx = fmaxf(mx, __shfl_xor(mx, 2));
            mx = fmaxf(mx, __shfl_xor(mx, 4));
            mx = fmaxf(mx, __shfl_xor(mx, 8));
            const float mnew = fmaxf(m[r], mx);
            const float a = __expf(m[r] - mnew);
            float ls = 0.f;
#pragma unroll
            for (int ni = 0; ni < 4; ++ni) { float e = __expf(sv[ni] - mnew); p[ni][r] = e; ls += e; }
            ls += __shfl_xor(ls, 1);
            ls += __shfl_xor(ls, 2);
            ls += __shfl_xor(ls, 4);
            ls += __shfl_xor(ls, 8);
            l[r] = l[r] * a + ls;
            m[r] = mnew;
#pragma unroll
            for (int ni = 0; ni < 4; ++ni) o[ni][r] *= a;
        }

        // ---- P (C-layout) -> wave-private LDS -> A-frags (same wave: no barrier) ----
#pragma unroll
        for (int ni = 0; ni < 4; ++ni)
#pragma unroll
            for (int r = 0; r < 4; ++r)
                Ps[(wq + quad * 4 + r) * LDK + ni * 16 + l16] = f2bf(p[ni][r]);

        const bf16x8 pf0 = *(const bf16x8*)&Ps[(wq + l16) * LDK + quad * 8];
        const bf16x8 pf1 = *(const bf16x8*)&Ps[(wq + l16) * LDK + 32 + quad * 8];
#pragma unroll
        for (int ni = 0; ni < 4; ++ni) {
            bf16x8 vf0 = *(const bf16x8*)&Vt[(ni * 16 + l16) * LDK + quad * 8];
            bf16x8 vf1 = *(const bf16x8*)&Vt[(ni * 16 + l16) * LDK + 32 + quad * 8];
            o[ni] = __builtin_amdgcn_mfma_f32_16x16x32_bf16(pf0, vf0, o[ni], 0, 0, 0);
            o[ni] = __builtin_amdgcn_mfma_f32_16x16x32_bf16(pf1, vf1, o[ni], 0, 0, 0);
        }
    }

    // ---- epilogue: Y[row][h*HS + ni*16 + l16] = O / l ----
    unsigned short* yrow = Y + (size_t)(b * T_SEQ + q0 + wq + quad * 4) * D_EMB + h * HS;
#pragma unroll
    for (int r = 0; r < 4; ++r) {
        const float inv = 1.0f / l[r];
#pragma unroll
        for (int ni = 0; ni < 4; ++ni)
            yrow[(size_t)r * D_EMB + ni * 16 + l16] = f2bf(o[ni][r] * inv);
    }
}

// ---------------- launch ----------------
extern "C" void kernel_launch(void* const* d_in, const int* in_sizes, int n_in,
                              void* d_out, int out_size, void* d_ws, size_t ws_size,
                              hipStream_t stream) {
    (void)in_sizes; (void)n_in; (void)out_size; (void)ws_size;
    const int*   tokens  = (const int*)  d_in[0];
    const float* tok_emb = (const float*)d_in[1];
    const float* pos_emb = (const float*)d_in[2];
    const float* ln1_g   = (const float*)d_in[3];
    const float* ln1_b   = (const float*)d_in[4];
    const float* Wq      = (const float*)d_in[5];
    const float* Wk      = (const float*)d_in[6];
    const float* Wv      = (const float*)d_in[7];
    const float* Wo      = (const float*)d_in[8];
    const float* bo      = (const float*)d_in[9];
    const float* ln2_g   = (const float*)d_in[10];
    const float* ln2_b   = (const float*)d_in[11];
    const float* W1      = (const float*)d_in[12];
    const float* b1      = (const float*)d_in[13];
    const float* W2      = (const float*)d_in[14];
    const float* b2      = (const float*)d_in[15];
    const float* lnf_g   = (const float*)d_in[16];
    const float* lnf_b   = (const float*)d_in[17];
    const float* Wlm     = (const float*)d_in[18];
    const float* blm     = (const float*)d_in[19];
    float* out = (float*)d_out;

    const int M = BSZ * T_SEQ;   // 2048

    char* p = (char*)d_ws;
    float*          x     = (float*)p;          p += (size_t)M * D_EMB * 4;        //  8 MB f32 residual
    unsigned short* qkv   = (unsigned short*)p; p += (size_t)M * QKVC  * 2;        //  6 MB bf16 fused q|k|v
    unsigned short* hbf   = (unsigned short*)p; p += (size_t)M * D_EMB * 2;        //  4 MB bf16 LN out
    unsigned short* ybf   = (unsigned short*)p; p += (size_t)M * D_EMB * 2;        //  4 MB bf16 attn out
    unsigned short* ffnbf = (unsigned short*)p; p += (size_t)M * FFH   * 2;        // 16 MB bf16 relu out
    unsigned short* qkvT  = (unsigned short*)p; p += (size_t)QKVC * D_EMB * 2;     //  3 MB W_qkv^T
    unsigned short* WoT   = (unsigned short*)p; p += (size_t)D_EMB * D_EMB * 2;    //  2 MB
    unsigned short* W1T   = (unsigned short*)p; p += (size_t)FFH * D_EMB * 2;      //  8 MB
    unsigned short* W2T   = (unsigned short*)p; p += (size_t)D_EMB * FFH * 2;      //  8 MB
    unsigned short* WlmT  = (unsigned short*)p; p += (size_t)VOCAB * D_EMB * 2;    // 64 MB

    embed_kernel<<<M, 256, 0, stream>>>(tokens, tok_emb, pos_emb, x);

    for (int l = 0; l < NL; ++l) {
        wconv6_kernel<<<10752, 256, 0, stream>>>(
            Wq + (size_t)l * D_EMB * D_EMB, Wk + (size_t)l * D_EMB * NKV * HS,
            Wv + (size_t)l * D_EMB * NKV * HS, Wo + (size_t)l * D_EMB * D_EMB,
            W1 + (size_t)l * D_EMB * FFH, W2 + (size_t)l * FFH * D_EMB,
            qkvT, WoT, W1T, W2T);
        ln_kernel<<<M, 256, 0, stream>>>(x, ln1_g + l * D_EMB, ln1_b + l * D_EMB, hbf);
        gemm_kernel<0,0,0,1><<<dim3(M/128, QKVC/128), 256, 0, stream>>>(
            hbf, qkvT, nullptr, nullptr, qkv, M, QKVC, D_EMB);
        attn_kernel<<<dim3(T_SEQ/64, NH, BSZ), 256, 0, stream>>>(qkv, ybf);
        gemm_kernel<1,1,0,0><<<dim3(M/128, D_EMB/128), 256, 0, stream>>>(
            ybf, WoT, bo + l * D_EMB, x, x, M, D_EMB, D_EMB);
        ln_kernel<<<M, 256, 0, stream>>>(x, ln2_g + l * D_EMB, ln2_b + l * D_EMB, hbf);
        gemm_kernel<1,0,1,1><<<dim3(M/128, FFH/128), 256, 0, stream>>>(
            hbf, W1T, b1 + l * FFH, nullptr, ffnbf, M, FFH, D_EMB);
        gemm_kernel<1,1,0,0><<<dim3(M/128, D_EMB/128), 256, 0, stream>>>(
            ffnbf, W2T, b2 + l * D_EMB, x, x, M, D_EMB, FFH);
    }
    ln_kernel<<<M, 256, 0, stream>>>(x, lnf_g, lnf_b, hbf);
    wconv_kernel<<<dim3(D_EMB/32, VOCAB/32), 256, 0, stream>>>(Wlm, WlmT, D_EMB, VOCAB);
    gemm_kernel<1,0,0,0><<<dim3(M/128, VOCAB/128), 256, 0, stream>>>(
        hbf, WlmT, blm, nullptr, out, M, VOCAB, D_EMB);
}